// Round 1
// baseline (45.241 us; speedup 1.0000x reference)
//
#include <hip/hip_runtime.h>

// out(x) = sum_{k=0..30} sigmoid(100*(x - (-15.5 + k))) - 16
// Offsets are 1.0 apart with sharpness 100 => only the NEAREST offset's
// sigmoid is non-saturated (all others are within 2e-22 of 0 or 1).
// Exact-to-fp32 closed form:
//   t = x + 15.5; j = clamp(rint(t), 0, 30); d = t - j
//   out = j + 1/(1 + exp(-100*d)) - 16
// => 1 exp + 1 rcp per element instead of 31 sigmoids. Memory-bound.

__device__ __forceinline__ float staircase(float x) {
    float t = x + 15.5f;
    float j = rintf(t);                       // v_rndne_f32
    j = fminf(fmaxf(j, 0.0f), 30.0f);         // clamp to valid offset range
    float d = t - j;                          // d in [-0.5, 0.5] (or beyond if clamped)
    // exp(-100*d) = exp2(-100*log2(e)*d); arg bounded ~|72| in-range, extremes
    // saturate correctly: exp2(+big)=inf -> rcp=0 ; exp2(-big)=0 -> rcp(1)=1.
    float e = __builtin_amdgcn_exp2f(d * -144.26950408889634f);
    float s = __builtin_amdgcn_rcpf(1.0f + e);
    return j + s - 16.0f;
}

__global__ __launch_bounds__(256) void Roundings_24154896073503_kernel(
        const float* __restrict__ x, float* __restrict__ out, int n4) {
    const float4* __restrict__ x4 = reinterpret_cast<const float4*>(x);
    float4* __restrict__ o4 = reinterpret_cast<float4*>(out);
    int idx = blockIdx.x * blockDim.x + threadIdx.x;
    int stride = gridDim.x * blockDim.x;
    for (int i = idx; i < n4; i += stride) {
        float4 v = x4[i];
        float4 r;
        r.x = staircase(v.x);
        r.y = staircase(v.y);
        r.z = staircase(v.z);
        r.w = staircase(v.w);
        o4[i] = r;
    }
}

// Tail handler for n not divisible by 4 (not expected here: 4096*8192 % 4 == 0,
// but keep correctness general).
__global__ void Roundings_tail_kernel(const float* __restrict__ x,
                                      float* __restrict__ out, int start, int n) {
    int i = start + blockIdx.x * blockDim.x + threadIdx.x;
    if (i < n) out[i] = staircase(x[i]);
}

extern "C" void kernel_launch(void* const* d_in, const int* in_sizes, int n_in,
                              void* d_out, int out_size, void* d_ws, size_t ws_size,
                              hipStream_t stream) {
    const float* x = (const float*)d_in[0];
    float* out = (float*)d_out;
    int n = in_sizes[0];
    int n4 = n / 4;

    const int block = 256;
    // Memory-bound: cap grid at ~8 blocks/CU * 256 CU and grid-stride.
    int grid = (n4 + block - 1) / block;
    if (grid > 2048) grid = 2048;
    if (grid > 0) {
        Roundings_24154896073503_kernel<<<grid, block, 0, stream>>>(x, out, n4);
    }

    int done = n4 * 4;
    int rem = n - done;
    if (rem > 0) {
        int tgrid = (rem + block - 1) / block;
        Roundings_tail_kernel<<<tgrid, block, 0, stream>>>(x, out, done, n);
    }
}